// Round 8
// baseline (112.312 us; speedup 1.0000x reference)
//
#include <hip/hip_runtime.h>
#include <math.h>

// Problem constants (from setup_inputs): B=2, V=10000, N=16, CIN=128, COUT=64
#define V_CNT 10000
#define NB 16
#define TQ 16          // queries per block (R8: back to 16; R7's TQ=8 doubled
                       // per-thread prologue/epilogue cost and tripled bank
                       // conflicts for zero occupancy gain)
#define BQ_TOTAL 20000 // B*V

// NOTE (R6 discovery): the harness re-poisons the 256MiB workspace with a
// fillBuffer EVERY timed iteration (~42us at HBM peak) plus ~15us dispatch
// overhead + ~3us prep. Only fold (~40us) is attackable.

// ws float layout (weight scratch only):
//   [0, 2880)        W45T[kj][d]    (45 x 64, kj-major, float4-aligned rows)
//   [2880, 2925)     Wdir9[kj]      (45)
//   [2944, 3004)     FN[f*3+axis]   (20 x 3 face normals)
#define WS_W45T  0
#define WS_WD9   2880
#define WS_FN    2944

typedef float f32x2 __attribute__((ext_vector_type(2)));

// _FTC permutation table (runtime-indexed -> device constant memory)
__device__ __constant__ int FTC_d[20][5] = {
  {1,4,0,2,3},{2,0,1,4,3},{3,1,0,4,2},{4,2,0,3,1},{0,3,1,2,4},
  {3,2,0,4,1},{4,3,0,2,1},{0,4,1,2,3},{1,0,2,4,3},{2,1,0,4,3},
  {4,0,1,3,2},{0,1,2,3,4},{1,2,0,3,4},{2,3,0,1,4},{3,4,0,1,2},
  {1,3,0,2,4},{0,2,1,3,4},{4,1,0,3,2},{3,0,1,4,2},{2,4,0,1,3}};

// faces grouped by color: RBYCOL[s][m] = m-th face r with FTC[r][0]==s.
__device__ __constant__ int RBYCOL_d[5][4] = {
  {4,7,11,16},{0,8,12,15},{1,9,13,19},{2,5,14,18},{3,6,10,17}};

// color of face f = _FTC[f][0] (compile-time folded in unrolled loops)
constexpr int COLF[20] = {1,2,3,4,0,3,4,0,1,2,4,0,1,2,3,1,0,4,3,2};

// w9[k][j] = w19[W9MAP[k][j]]  (the _build_kernel row construction)
// Sharing structure exploited in Phase B:
//   k=0,1,8: positions 2,3,4 equal        -> dot uses (e2+e3+e4)
//   k=2,3,4: positions 0,1 all = w19[9],w19[10]  -> share c1
//   k=5,6,7: positions 0,1 all = w19[14],w19[15] -> share c2
constexpr int W9MAP[9][5] = {
  {0,1,2,2,2},{3,4,5,5,5},
  {9,10,11,12,13},{9,10,12,13,11},{9,10,13,11,12},
  {14,15,16,17,18},{14,15,17,18,16},{14,15,18,16,17},
  {6,7,8,8,8}};

__device__ __constant__ int FACES_d[20][3] = {
  {1,2,7},{1,3,7},{1,3,5},{1,4,5},{1,2,4},{2,7,8},{3,7,9},{3,5,11},{4,5,6},{2,4,10},
  {2,8,10},{7,8,9},{3,9,11},{5,6,11},{4,6,10},{0,8,10},{0,6,10},{0,6,11},{0,9,11},{0,8,9}};

#define PHI_F 1.61803398874989484820f
__device__ __constant__ float VS_d[12][3] = {
  {-1.f,PHI_F,0.f},{1.f,PHI_F,0.f},{-1.f,-PHI_F,0.f},{1.f,-PHI_F,0.f},
  {0.f,-1.f,PHI_F},{0.f,1.f,PHI_F},{0.f,-1.f,-PHI_F},{0.f,1.f,-PHI_F},
  {PHI_F,0.f,-1.f},{PHI_F,0.f,1.f},{-PHI_F,0.f,-1.f},{-PHI_F,0.f,1.f}};

__device__ __forceinline__ float fast_tanh(float x){
  // |x| <= 1 here (dot of unit vectors), no overflow concerns
  float e = __expf(2.0f * x);
  return 1.0f - 2.0f * __builtin_amdgcn_rcpf(e + 1.0f);
}

// ---------------------------------------------------------------------------
// Kernel 1: weight prep. Blocks 0..63: W45T[.][d] = w9(sum_c W[d,c,:]),
//           written TRANSPOSED (kj-major) so fold's Stage0 is a linear copy.
//           Block 64: Wdir9 = w9(sum_c W_dir[c,:]) + face normals.
// ---------------------------------------------------------------------------
__global__ __launch_bounds__(128) void prep_kernel(const float* __restrict__ W,
                                                   const float* __restrict__ Wdir,
                                                   float* __restrict__ ws){
  __shared__ float buf[128][20];   // pad 19->20 to break bank stride
  __shared__ float w19s[19];
  int d = blockIdx.x;   // 0..64
  int c = threadIdx.x;  // 0..127  (one per CIN)

  const float* src = (d < 64) ? (W + ((size_t)d*128 + c)*19) : (Wdir + (size_t)c*19);
  #pragma unroll
  for (int tt = 0; tt < 19; ++tt) buf[c][tt] = src[tt];

  if (d == 64 && c < 20){
    float x=0.f, y=0.f, z=0.f;
    #pragma unroll
    for (int vv=0; vv<3; ++vv){
      int vi = FACES_d[c][vv];
      x += VS_d[vi][0]; y += VS_d[vi][1]; z += VS_d[vi][2];
    }
    float inv = rsqrtf(x*x + y*y + z*z);
    ws[WS_FN + c*3 + 0] = x*inv;
    ws[WS_FN + c*3 + 1] = y*inv;
    ws[WS_FN + c*3 + 2] = z*inv;
  }
  __syncthreads();

  if (c < 19){
    float s = 0.f;
    for (int i = 0; i < 128; ++i) s += buf[i][c];
    w19s[c] = s;
  }
  __syncthreads();

  if (c < 45){
    int k = c / 5, j = c % 5;
    float v = w19s[W9MAP[k][j]];
    if (d < 64) ws[WS_W45T + c*64 + d] = v;     // transposed [kj][d]
    else        ws[WS_WD9  + c]        = v;
  }
}

// ---------------------------------------------------------------------------
// Kernel 2 (fused): per block: TQ=16 queries -> FINAL output.
//  Stage0: LINEAR copy ws->W45T LDS (conflict-free).
//  Phase A (256 thr = 16q x 16n): de5 color sums, stored COLOR-MAJOR
//          de5s[q][j][n] (row stride 20 words: banks f*20%32 ={0,20,8,28,16},
//          disjoint) so Phase B loads n-PAIRS with ds_read_b64 + imm offsets.
//  Phase B (320 thr = 16q x 5color x 4member): acc[45] (f32x2-paired for
//          v_pk_fma lowering) over 8 n-pair iters; shared c1/c2 dot partials;
//          quad-reduce via 2x __shfl_xor; m==0 writes col to Ps2T[kj][col].
//  Phase C (160 thr = 8 d-oct x 20 colquad): 64x45 @ 45x80 GEMM from LDS,
//          8x4 register tile (-25% LDS traffic vs 4x4); float4 stores.
//  __launch_bounds__(320) ONLY (R5: a min-waves floor caps VGPRs -> spill).
//  VGPR budget note: <=73 keeps 5 blocks/CU resident (7 waves/SIMD on the
//  loaded SIMDs); >85 would drop to 4 blocks/CU.
// ---------------------------------------------------------------------------
__global__ __launch_bounds__(320) void fold_kernel(const int*   __restrict__ nbr,
                                                   const float* __restrict__ verts,
                                                   const float* __restrict__ ws,
                                                   float* __restrict__ out){
  __shared__ float de5s[TQ][5][20];        // 6400 B   [q][color][n(pad20)]
  __shared__ float Ps2T[45][80];           // 14400 B  [kj][col]
  __shared__ float W45T[45][64];           // 11520 B  [kj][d]
  int t = threadIdx.x;
  int blockq0 = blockIdx.x * TQ;

  // ---- Stage0: linear, coalesced, conflict-free copy (2880 = 9*320) ----
  {
    float* wl = &W45T[0][0];
    #pragma unroll
    for (int sW = 0; sW < 9; ++sW) wl[t + sW*320] = ws[WS_W45T + t + sW*320];
  }

  // ---- Phase A ----
  if (t < TQ*NB){
    int ql = t >> 4;
    int n  = t & 15;
    int qg = blockq0 + ql;                       // 0..19999
    int q  = (qg >= V_CNT) ? (qg - V_CNT) : qg;
    int b0 = qg - q;                              // 0 or 10000
    int idx = nbr[qg*NB + n];
    float vx = verts[qg*3+0], vy = verts[qg*3+1], vz = verts[qg*3+2];
    const float* nv = verts + (size_t)(b0 + idx)*3;
    float dx = nv[0]-vx, dy = nv[1]-vy, dz = nv[2]-vz;
    float dd = dx*dx + dy*dy + dz*dz;
    float inv = (dd > 0.f) ? rsqrtf(dd) : 0.f;    // ref: d/max(||d||,1e-12); exact-0 -> 0
    dx *= inv; dy *= inv; dz *= inv;
    const float* fnp = ws + WS_FN;                // uniform -> scalar loads
    float s0=0.f, s1=0.f, s2=0.f, s3=0.f, s4=0.f;
    #pragma unroll
    for (int f = 0; f < 20; ++f){
      float x = fnp[f*3+0]*dx + fnp[f*3+1]*dy + fnp[f*3+2]*dz;
      float th = fast_tanh(x);
      if      (COLF[f]==0) s0 += th;
      else if (COLF[f]==1) s1 += th;
      else if (COLF[f]==2) s2 += th;
      else if (COLF[f]==3) s3 += th;
      else                 s4 += th;
    }
    de5s[ql][0][n]=s0; de5s[ql][1][n]=s1; de5s[ql][2][n]=s2;
    de5s[ql][3][n]=s3; de5s[ql][4][n]=s4;
  }
  __syncthreads();

  // ---- Phase B ----
  {
    int ql = t / 20;
    int g  = t - ql*20;          // 0..19
    int s  = g >> 2;             // color 0..4
    int m  = g & 3;              // quad member 0..3
    int r  = RBYCOL_d[s][m];     // face handled by this lane
    int f0 = FTC_d[r][0], f1 = FTC_d[r][1], f2 = FTC_d[r][2],
        f3 = FTC_d[r][3], f4 = FTC_d[r][4];     // f0 == s by construction

    // n-pair base pointers (b64 loads, imm offsets 0..56)
    const f32x2* P0 = (const f32x2*)&de5s[ql][0][0] + f0*10;
    const f32x2* P1 = (const f32x2*)&de5s[ql][0][0] + f1*10;
    const f32x2* P2 = (const f32x2*)&de5s[ql][0][0] + f2*10;
    const f32x2* P3 = (const f32x2*)&de5s[ql][0][0] + f3*10;
    const f32x2* P4 = (const f32x2*)&de5s[ql][0][0] + f4*10;

    float wdl[45];
    #pragma unroll
    for (int i = 0; i < 45; ++i) wdl[i] = ws[WS_WD9 + i];  // uniform -> SGPR

    f32x2 acc01[9], acc23[9];
    float acc4[9];
    #pragma unroll
    for (int k = 0; k < 9; ++k){ acc01[k] = (f32x2)0.f; acc23[k] = (f32x2)0.f; acc4[k] = 0.f; }

    #pragma unroll
    for (int np = 0; np < 8; ++np){
      f32x2 E0 = P0[np], E1 = P1[np], E2 = P2[np], E3 = P3[np], E4 = P4[np];
      #pragma unroll
      for (int h = 0; h < 2; ++h){
        float e0 = (h==0)?E0.x:E0.y, e1 = (h==0)?E1.x:E1.y,
              e2 = (h==0)?E2.x:E2.y, e3 = (h==0)?E3.x:E3.y,
              e4 = (h==0)?E4.x:E4.y;
        float e234 = e2 + e3 + e4;
        float c1 = wdl[10]*e0 + wdl[11]*e1;      // shared by k=2,3,4
        float c2 = wdl[25]*e0 + wdl[26]*e1;      // shared by k=5,6,7
        float a[9];
        a[0] = fmaxf(wdl[ 0]*e0 + wdl[ 1]*e1 + wdl[ 2]*e234, 0.f);
        a[1] = fmaxf(wdl[ 5]*e0 + wdl[ 6]*e1 + wdl[ 7]*e234, 0.f);
        a[2] = fmaxf(c1 + wdl[12]*e2 + wdl[13]*e3 + wdl[14]*e4, 0.f);
        a[3] = fmaxf(c1 + wdl[17]*e2 + wdl[18]*e3 + wdl[19]*e4, 0.f);
        a[4] = fmaxf(c1 + wdl[22]*e2 + wdl[23]*e3 + wdl[24]*e4, 0.f);
        a[5] = fmaxf(c2 + wdl[27]*e2 + wdl[28]*e3 + wdl[29]*e4, 0.f);
        a[6] = fmaxf(c2 + wdl[32]*e2 + wdl[33]*e3 + wdl[34]*e4, 0.f);
        a[7] = fmaxf(c2 + wdl[37]*e2 + wdl[38]*e3 + wdl[39]*e4, 0.f);
        a[8] = fmaxf(wdl[40]*e0 + wdl[41]*e1 + wdl[42]*e234, 0.f);
        f32x2 e01; e01.x = e0; e01.y = e1;
        f32x2 e23; e23.x = e2; e23.y = e3;
        #pragma unroll
        for (int k = 0; k < 9; ++k){
          f32x2 av; av.x = a[k]; av.y = a[k];
          acc01[k] += av * e01;                  // -> v_pk_fma_f32
          acc23[k] += av * e23;
          acc4[k]  += a[k] * e4;
        }
      }
    }
    // quad reduction across the 4 faces of this color (lanes 4-aligned,
    // masks 1,2 stay inside the quad; 64%4==0 so never cross-wave)
    #pragma unroll
    for (int k = 0; k < 9; ++k){
      acc01[k].x += __shfl_xor(acc01[k].x, 1); acc01[k].x += __shfl_xor(acc01[k].x, 2);
      acc01[k].y += __shfl_xor(acc01[k].y, 1); acc01[k].y += __shfl_xor(acc01[k].y, 2);
      acc23[k].x += __shfl_xor(acc23[k].x, 1); acc23[k].x += __shfl_xor(acc23[k].x, 2);
      acc23[k].y += __shfl_xor(acc23[k].y, 1); acc23[k].y += __shfl_xor(acc23[k].y, 2);
      acc4[k]    += __shfl_xor(acc4[k],    1); acc4[k]    += __shfl_xor(acc4[k],    2);
    }
    if (m == 0){
      int col = ql*5 + s;
      #pragma unroll
      for (int k = 0; k < 9; ++k){
        Ps2T[k*5+0][col] = acc01[k].x;
        Ps2T[k*5+1][col] = acc01[k].y;
        Ps2T[k*5+2][col] = acc23[k].x;
        Ps2T[k*5+3][col] = acc23[k].y;
        Ps2T[k*5+4][col] = acc4[k];
      }
    }
  }
  __syncthreads();

  // ---- Phase C: out[d, col] = sum_kj W45T[kj][d] * Ps2T[kj][col] ----
  // 8x4 tile, 160 active threads: block LDS traffic 345KB (4x4 was 460KB).
  if (t < 160){
    int dq = t / 20;             // 0..7 -> d0 = dq*8
    int cq = t - dq*20;          // 0..19 -> col0 = cq*4 (inner for coalescing)
    f32x2 acc[8][2];
    #pragma unroll
    for (int r = 0; r < 8; ++r){ acc[r][0] = (f32x2)0.f; acc[r][1] = (f32x2)0.f; }
    #pragma unroll 5
    for (int kj = 0; kj < 45; ++kj){
      float4 w0 = *(const float4*)&W45T[kj][dq*8];
      float4 w1 = *(const float4*)&W45T[kj][dq*8+4];
      float4 p  = *(const float4*)&Ps2T[kj][cq*4];
      f32x2 p01; p01.x = p.x; p01.y = p.y;
      f32x2 p23; p23.x = p.z; p23.y = p.w;
      float wr[8] = {w0.x,w0.y,w0.z,w0.w, w1.x,w1.y,w1.z,w1.w};
      #pragma unroll
      for (int r = 0; r < 8; ++r){
        f32x2 wv; wv.x = wr[r]; wv.y = wr[r];
        acc[r][0] += wv * p01;
        acc[r][1] += wv * p23;
      }
    }
    int b   = (blockq0 >= V_CNT) ? 1 : 0;
    int lq0 = blockq0 - b*V_CNT;
    float* ob = out + (size_t)b*3200000 + (size_t)lq0*5 + cq*4;
    int d0 = dq*8;
    #pragma unroll
    for (int r = 0; r < 8; ++r){
      *(float4*)&ob[(size_t)(d0+r)*50000] =
        make_float4(acc[r][0].x, acc[r][0].y, acc[r][1].x, acc[r][1].y);
    }
  }
}

extern "C" void kernel_launch(void* const* d_in, const int* in_sizes, int n_in,
                              void* d_out, int out_size, void* d_ws, size_t ws_size,
                              hipStream_t stream){
  const int*   nbr   = (const int*)d_in[0];
  const float* verts = (const float*)d_in[1];
  const float* W     = (const float*)d_in[2];
  const float* Wdir  = (const float*)d_in[3];
  float* out = (float*)d_out;
  float* ws  = (float*)d_ws;           // ~12 KB weight scratch

  hipLaunchKernelGGL(prep_kernel, dim3(65), dim3(128), 0, stream, W, Wdir, ws);
  hipLaunchKernelGGL(fold_kernel, dim3(BQ_TOTAL/TQ), dim3(320), 0, stream, nbr, verts, ws, out);
}

// Round 9
// 103.975 us; speedup vs baseline: 1.0802x; 1.0802x over previous
//
#include <hip/hip_runtime.h>
#include <math.h>

// Problem constants (from setup_inputs): B=2, V=10000, N=16, CIN=128, COUT=64
#define V_CNT 10000
#define NB 16
#define TQ 16          // queries per block
#define BQ_TOTAL 20000 // B*V

// NOTE (R6 discovery): the harness re-poisons the 256MiB workspace with a
// fillBuffer EVERY timed iteration (~42us at HBM peak) plus ~15us dispatch
// overhead + ~3us prep. Only fold is attackable.
// NOTE (R8 lesson): VGPR=76 crossed the 64-reg cliff -> waves/SIMD halved,
// fold 40->50us. Phase B is k-CHUNKED (25/20 accs) to stay under 64.

// ws float layout (weight scratch only):
//   [0, 2880)        W45T[kj][d]    (45 x 64, kj-major, float4-aligned rows)
//   [2880, 2925)     Wdir9[kj]      (45)
//   [2944, 3004)     FN[f*3+axis]   (20 x 3 face normals)
#define WS_W45T  0
#define WS_WD9   2880
#define WS_FN    2944

typedef float f32x2 __attribute__((ext_vector_type(2)));

// _FTC permutation table (runtime-indexed -> device constant memory)
__device__ __constant__ int FTC_d[20][5] = {
  {1,4,0,2,3},{2,0,1,4,3},{3,1,0,4,2},{4,2,0,3,1},{0,3,1,2,4},
  {3,2,0,4,1},{4,3,0,2,1},{0,4,1,2,3},{1,0,2,4,3},{2,1,0,4,3},
  {4,0,1,3,2},{0,1,2,3,4},{1,2,0,3,4},{2,3,0,1,4},{3,4,0,1,2},
  {1,3,0,2,4},{0,2,1,3,4},{4,1,0,3,2},{3,0,1,4,2},{2,4,0,1,3}};

// faces grouped by color: RBYCOL[s][m] = m-th face r with FTC[r][0]==s.
__device__ __constant__ int RBYCOL_d[5][4] = {
  {4,7,11,16},{0,8,12,15},{1,9,13,19},{2,5,14,18},{3,6,10,17}};

// color of face f = _FTC[f][0] (compile-time folded in unrolled loops)
constexpr int COLF[20] = {1,2,3,4,0,3,4,0,1,2,4,0,1,2,3,1,0,4,3,2};

// w9[k][j] = w19[W9MAP[k][j]]  (the _build_kernel row construction)
// Sharing structure exploited in Phase B:
//   k=0,1,8: positions 2,3,4 equal               -> dot uses (e2+e3+e4)
//   k=2,3,4: positions 0,1 all = w19[9],w19[10]  -> share c1
//   k=5,6,7: positions 0,1 all = w19[14],w19[15] -> share c2
constexpr int W9MAP[9][5] = {
  {0,1,2,2,2},{3,4,5,5,5},
  {9,10,11,12,13},{9,10,12,13,11},{9,10,13,11,12},
  {14,15,16,17,18},{14,15,17,18,16},{14,15,18,16,17},
  {6,7,8,8,8}};

__device__ __constant__ int FACES_d[20][3] = {
  {1,2,7},{1,3,7},{1,3,5},{1,4,5},{1,2,4},{2,7,8},{3,7,9},{3,5,11},{4,5,6},{2,4,10},
  {2,8,10},{7,8,9},{3,9,11},{5,6,11},{4,6,10},{0,8,10},{0,6,10},{0,6,11},{0,9,11},{0,8,9}};

#define PHI_F 1.61803398874989484820f
__device__ __constant__ float VS_d[12][3] = {
  {-1.f,PHI_F,0.f},{1.f,PHI_F,0.f},{-1.f,-PHI_F,0.f},{1.f,-PHI_F,0.f},
  {0.f,-1.f,PHI_F},{0.f,1.f,PHI_F},{0.f,-1.f,-PHI_F},{0.f,1.f,-PHI_F},
  {PHI_F,0.f,-1.f},{PHI_F,0.f,1.f},{-PHI_F,0.f,-1.f},{-PHI_F,0.f,1.f}};

__device__ __forceinline__ float fast_tanh(float x){
  // |x| <= 1 here (dot of unit vectors), no overflow concerns
  float e = __expf(2.0f * x);
  return 1.0f - 2.0f * __builtin_amdgcn_rcpf(e + 1.0f);
}

// ---------------------------------------------------------------------------
// Kernel 1: weight prep. Blocks 0..63: W45T[.][d] = w9(sum_c W[d,c,:]),
//           written TRANSPOSED (kj-major) so fold's Stage0 is a linear copy.
//           Block 64: Wdir9 = w9(sum_c W_dir[c,:]) + face normals.
// ---------------------------------------------------------------------------
__global__ __launch_bounds__(128) void prep_kernel(const float* __restrict__ W,
                                                   const float* __restrict__ Wdir,
                                                   float* __restrict__ ws){
  __shared__ float buf[128][20];   // pad 19->20 to break bank stride
  __shared__ float w19s[19];
  int d = blockIdx.x;   // 0..64
  int c = threadIdx.x;  // 0..127  (one per CIN)

  const float* src = (d < 64) ? (W + ((size_t)d*128 + c)*19) : (Wdir + (size_t)c*19);
  #pragma unroll
  for (int tt = 0; tt < 19; ++tt) buf[c][tt] = src[tt];

  if (d == 64 && c < 20){
    float x=0.f, y=0.f, z=0.f;
    #pragma unroll
    for (int vv=0; vv<3; ++vv){
      int vi = FACES_d[c][vv];
      x += VS_d[vi][0]; y += VS_d[vi][1]; z += VS_d[vi][2];
    }
    float inv = rsqrtf(x*x + y*y + z*z);
    ws[WS_FN + c*3 + 0] = x*inv;
    ws[WS_FN + c*3 + 1] = y*inv;
    ws[WS_FN + c*3 + 2] = z*inv;
  }
  __syncthreads();

  if (c < 19){
    float s = 0.f;
    for (int i = 0; i < 128; ++i) s += buf[i][c];
    w19s[c] = s;
  }
  __syncthreads();

  if (c < 45){
    int k = c / 5, j = c % 5;
    float v = w19s[W9MAP[k][j]];
    if (d < 64) ws[WS_W45T + c*64 + d] = v;     // transposed [kj][d]
    else        ws[WS_WD9  + c]        = v;
  }
}

// ---------------------------------------------------------------------------
// Kernel 2 (fused): per block: TQ=16 queries -> FINAL output.
//  Stage0: LINEAR copy ws->W45T LDS (conflict-free).
//  Phase A (256 thr = 16q x 16n): de5 color sums, stored COLOR-MAJOR
//          de5s[q][j][n] (n-pairs readable with ds_read_b64 + imm offsets).
//  Phase B (320 thr = 16q x 5color x 4member): TWO k-chunks (k=0..4 with
//          shared c1, then k=5..8 with shared c2) so peak live regs =
//          25 acc + 10 E + ~11 other < 64 (the R8 cliff). Per chunk: 8
//          ds_read_b64 n-pair loads per face, e234 fold, immediate per-k
//          f32x2 accumulate, quad-reduce (2x shfl_xor), m==0 writes cols.
//          asm memory clobber between chunks stops LLVM re-CSEing the
//          second chunk's LDS loads into chunk-spanning live ranges.
//  Phase C (320 thr = 16 dquad x 20 colquad): 64x45 @ 45x80 GEMM from LDS,
//          4x4 register tile (register-light, proven in R6); float4 stores.
//  __launch_bounds__(320) ONLY (R5: a min-waves floor caps VGPRs -> spill).
// ---------------------------------------------------------------------------
__global__ __launch_bounds__(320) void fold_kernel(const int*   __restrict__ nbr,
                                                   const float* __restrict__ verts,
                                                   const float* __restrict__ ws,
                                                   float* __restrict__ out){
  __shared__ float de5s[TQ][5][20];        // 6400 B   [q][color][n(pad20)]
  __shared__ float Ps2T[45][80];           // 14400 B  [kj][col]
  __shared__ float W45T[45][64];           // 11520 B  [kj][d]
  int t = threadIdx.x;
  int blockq0 = blockIdx.x * TQ;

  // ---- Stage0: linear, coalesced, conflict-free copy (2880 = 9*320) ----
  {
    float* wl = &W45T[0][0];
    #pragma unroll
    for (int sW = 0; sW < 9; ++sW) wl[t + sW*320] = ws[WS_W45T + t + sW*320];
  }

  // ---- Phase A ----
  if (t < TQ*NB){
    int ql = t >> 4;
    int n  = t & 15;
    int qg = blockq0 + ql;                       // 0..19999
    int q  = (qg >= V_CNT) ? (qg - V_CNT) : qg;
    int b0 = qg - q;                              // 0 or 10000
    int idx = nbr[qg*NB + n];
    float vx = verts[qg*3+0], vy = verts[qg*3+1], vz = verts[qg*3+2];
    const float* nv = verts + (size_t)(b0 + idx)*3;
    float dx = nv[0]-vx, dy = nv[1]-vy, dz = nv[2]-vz;
    float dd = dx*dx + dy*dy + dz*dz;
    float inv = (dd > 0.f) ? rsqrtf(dd) : 0.f;    // ref: d/max(||d||,1e-12); exact-0 -> 0
    dx *= inv; dy *= inv; dz *= inv;
    const float* fnp = ws + WS_FN;                // uniform -> scalar loads
    float s0=0.f, s1=0.f, s2=0.f, s3=0.f, s4=0.f;
    #pragma unroll
    for (int f = 0; f < 20; ++f){
      float x = fnp[f*3+0]*dx + fnp[f*3+1]*dy + fnp[f*3+2]*dz;
      float th = fast_tanh(x);
      if      (COLF[f]==0) s0 += th;
      else if (COLF[f]==1) s1 += th;
      else if (COLF[f]==2) s2 += th;
      else if (COLF[f]==3) s3 += th;
      else                 s4 += th;
    }
    de5s[ql][0][n]=s0; de5s[ql][1][n]=s1; de5s[ql][2][n]=s2;
    de5s[ql][3][n]=s3; de5s[ql][4][n]=s4;
  }
  __syncthreads();

  // ---- Phase B (two k-chunks, each register-light) ----
  {
    int ql = t / 20;
    int g  = t - ql*20;          // 0..19
    int s  = g >> 2;             // color 0..4
    int m  = g & 3;              // quad member 0..3
    int r  = RBYCOL_d[s][m];     // face handled by this lane
    int f0 = FTC_d[r][0], f1 = FTC_d[r][1], f2 = FTC_d[r][2],
        f3 = FTC_d[r][3], f4 = FTC_d[r][4];     // f0 == s by construction

    // n-pair base pointers (b64 loads, imm offsets 0..56)
    const f32x2* P0 = (const f32x2*)&de5s[ql][0][0] + f0*10;
    const f32x2* P1 = (const f32x2*)&de5s[ql][0][0] + f1*10;
    const f32x2* P2 = (const f32x2*)&de5s[ql][0][0] + f2*10;
    const f32x2* P3 = (const f32x2*)&de5s[ql][0][0] + f3*10;
    const f32x2* P4 = (const f32x2*)&de5s[ql][0][0] + f4*10;

    float wdl[45];
    #pragma unroll
    for (int i = 0; i < 45; ++i) wdl[i] = ws[WS_WD9 + i];  // uniform -> SGPR
    int col = ql*5 + s;

    // ===== chunk 0: k = 0..4 (acc 25 floats; c1 shared by k=2,3,4) =====
    {
      f32x2 a01[5], a23[5]; float a4[5];
      #pragma unroll
      for (int k = 0; k < 5; ++k){ a01[k] = (f32x2)0.f; a23[k] = (f32x2)0.f; a4[k] = 0.f; }
      #pragma unroll
      for (int np = 0; np < 8; ++np){
        f32x2 E0 = P0[np], E1 = P1[np], E2 = P2[np], E3 = P3[np], E4 = P4[np];
        #pragma unroll
        for (int h = 0; h < 2; ++h){
          float e0 = (h==0)?E0.x:E0.y, e1 = (h==0)?E1.x:E1.y,
                e2 = (h==0)?E2.x:E2.y, e3 = (h==0)?E3.x:E3.y,
                e4 = (h==0)?E4.x:E4.y;
          float e234 = e2 + e3 + e4;
          float c1 = wdl[10]*e0 + wdl[11]*e1;
          f32x2 e01; e01.x = e0; e01.y = e1;
          f32x2 e23; e23.x = e2; e23.y = e3;
          #pragma unroll
          for (int k = 0; k < 5; ++k){
            float a;
            if      (k == 0) a = wdl[ 0]*e0 + wdl[ 1]*e1 + wdl[ 2]*e234;
            else if (k == 1) a = wdl[ 5]*e0 + wdl[ 6]*e1 + wdl[ 7]*e234;
            else if (k == 2) a = c1 + wdl[12]*e2 + wdl[13]*e3 + wdl[14]*e4;
            else if (k == 3) a = c1 + wdl[17]*e2 + wdl[18]*e3 + wdl[19]*e4;
            else             a = c1 + wdl[22]*e2 + wdl[23]*e3 + wdl[24]*e4;
            a = fmaxf(a, 0.f);
            f32x2 av; av.x = a; av.y = a;
            a01[k] += av * e01;
            a23[k] += av * e23;
            a4[k]  += a * e4;
          }
        }
      }
      #pragma unroll
      for (int k = 0; k < 5; ++k){
        a01[k].x += __shfl_xor(a01[k].x,1); a01[k].x += __shfl_xor(a01[k].x,2);
        a01[k].y += __shfl_xor(a01[k].y,1); a01[k].y += __shfl_xor(a01[k].y,2);
        a23[k].x += __shfl_xor(a23[k].x,1); a23[k].x += __shfl_xor(a23[k].x,2);
        a23[k].y += __shfl_xor(a23[k].y,1); a23[k].y += __shfl_xor(a23[k].y,2);
        a4[k]    += __shfl_xor(a4[k],   1); a4[k]    += __shfl_xor(a4[k],   2);
      }
      if (m == 0){
        #pragma unroll
        for (int k = 0; k < 5; ++k){
          Ps2T[k*5+0][col] = a01[k].x;
          Ps2T[k*5+1][col] = a01[k].y;
          Ps2T[k*5+2][col] = a23[k].x;
          Ps2T[k*5+3][col] = a23[k].y;
          Ps2T[k*5+4][col] = a4[k];
        }
      }
    }
    asm volatile("" ::: "memory");   // no LDS-load CSE across chunks

    // ===== chunk 1: k = 5..8 (acc 20 floats; c2 shared by k=5,6,7) =====
    {
      f32x2 a01[4], a23[4]; float a4[4];
      #pragma unroll
      for (int k = 0; k < 4; ++k){ a01[k] = (f32x2)0.f; a23[k] = (f32x2)0.f; a4[k] = 0.f; }
      #pragma unroll
      for (int np = 0; np < 8; ++np){
        f32x2 E0 = P0[np], E1 = P1[np], E2 = P2[np], E3 = P3[np], E4 = P4[np];
        #pragma unroll
        for (int h = 0; h < 2; ++h){
          float e0 = (h==0)?E0.x:E0.y, e1 = (h==0)?E1.x:E1.y,
                e2 = (h==0)?E2.x:E2.y, e3 = (h==0)?E3.x:E3.y,
                e4 = (h==0)?E4.x:E4.y;
          float e234 = e2 + e3 + e4;
          float c2 = wdl[25]*e0 + wdl[26]*e1;
          f32x2 e01; e01.x = e0; e01.y = e1;
          f32x2 e23; e23.x = e2; e23.y = e3;
          #pragma unroll
          for (int k = 0; k < 4; ++k){
            float a;
            if      (k == 0) a = c2 + wdl[27]*e2 + wdl[28]*e3 + wdl[29]*e4;
            else if (k == 1) a = c2 + wdl[32]*e2 + wdl[33]*e3 + wdl[34]*e4;
            else if (k == 2) a = c2 + wdl[37]*e2 + wdl[38]*e3 + wdl[39]*e4;
            else             a = wdl[40]*e0 + wdl[41]*e1 + wdl[42]*e234;
            a = fmaxf(a, 0.f);
            f32x2 av; av.x = a; av.y = a;
            a01[k] += av * e01;
            a23[k] += av * e23;
            a4[k]  += a * e4;
          }
        }
      }
      #pragma unroll
      for (int k = 0; k < 4; ++k){
        a01[k].x += __shfl_xor(a01[k].x,1); a01[k].x += __shfl_xor(a01[k].x,2);
        a01[k].y += __shfl_xor(a01[k].y,1); a01[k].y += __shfl_xor(a01[k].y,2);
        a23[k].x += __shfl_xor(a23[k].x,1); a23[k].x += __shfl_xor(a23[k].x,2);
        a23[k].y += __shfl_xor(a23[k].y,1); a23[k].y += __shfl_xor(a23[k].y,2);
        a4[k]    += __shfl_xor(a4[k],   1); a4[k]    += __shfl_xor(a4[k],   2);
      }
      if (m == 0){
        #pragma unroll
        for (int k = 0; k < 4; ++k){
          Ps2T[25+k*5+0][col] = a01[k].x;
          Ps2T[25+k*5+1][col] = a01[k].y;
          Ps2T[25+k*5+2][col] = a23[k].x;
          Ps2T[25+k*5+3][col] = a23[k].y;
          Ps2T[25+k*5+4][col] = a4[k];
        }
      }
    }
  }
  __syncthreads();

  // ---- Phase C: out[d, col] = sum_kj W45T[kj][d] * Ps2T[kj][col] ----
  {
    int dq = t / 20;             // 0..15 -> d0 = dq*4
    int cq = t - dq*20;          // 0..19 -> col0 = cq*4 (inner for coalescing)
    float a00=0,a01=0,a02=0,a03=0, a10=0,a11=0,a12=0,a13=0,
          a20=0,a21=0,a22=0,a23=0, a30=0,a31=0,a32=0,a33=0;
    #pragma unroll
    for (int kj = 0; kj < 45; ++kj){
      float4 w = *(const float4*)&W45T[kj][dq*4];
      float4 p = *(const float4*)&Ps2T[kj][cq*4];
      a00 += w.x*p.x; a01 += w.x*p.y; a02 += w.x*p.z; a03 += w.x*p.w;
      a10 += w.y*p.x; a11 += w.y*p.y; a12 += w.y*p.z; a13 += w.y*p.w;
      a20 += w.z*p.x; a21 += w.z*p.y; a22 += w.z*p.z; a23 += w.z*p.w;
      a30 += w.w*p.x; a31 += w.w*p.y; a32 += w.w*p.z; a33 += w.w*p.w;
    }
    int b   = (blockq0 >= V_CNT) ? 1 : 0;
    int lq0 = blockq0 - b*V_CNT;
    float* ob = out + (size_t)b*3200000 + (size_t)lq0*5 + cq*4;
    int d0 = dq*4;
    *(float4*)&ob[(size_t)(d0+0)*50000] = make_float4(a00,a01,a02,a03);
    *(float4*)&ob[(size_t)(d0+1)*50000] = make_float4(a10,a11,a12,a13);
    *(float4*)&ob[(size_t)(d0+2)*50000] = make_float4(a20,a21,a22,a23);
    *(float4*)&ob[(size_t)(d0+3)*50000] = make_float4(a30,a31,a32,a33);
  }
}

extern "C" void kernel_launch(void* const* d_in, const int* in_sizes, int n_in,
                              void* d_out, int out_size, void* d_ws, size_t ws_size,
                              hipStream_t stream){
  const int*   nbr   = (const int*)d_in[0];
  const float* verts = (const float*)d_in[1];
  const float* W     = (const float*)d_in[2];
  const float* Wdir  = (const float*)d_in[3];
  float* out = (float*)d_out;
  float* ws  = (float*)d_ws;           // ~12 KB weight scratch

  hipLaunchKernelGGL(prep_kernel, dim3(65), dim3(128), 0, stream, W, Wdir, ws);
  hipLaunchKernelGGL(fold_kernel, dim3(BQ_TOTAL/TQ), dim3(320), 0, stream, nbr, verts, ws, out);
}